// Round 8
// baseline (120.594 us; speedup 1.0000x reference)
//
#include <hip/hip_runtime.h>
#include <stdint.h>
#include <stddef.h>

typedef __attribute__((ext_vector_type(8))) short short8;
typedef __attribute__((ext_vector_type(4))) short short4v;
typedef __attribute__((ext_vector_type(16))) float f32x16;

typedef const __attribute__((address_space(3))) char* lds_cp;

#define GLDS16(gp, lp)                                                        \
    __builtin_amdgcn_global_load_lds(                                         \
        (const __attribute__((address_space(1))) void*)(gp),                  \
        (__attribute__((address_space(3))) void*)(lp), 16, 0, 0)

// Opaque LDS read: no compiler-inserted waits; completion via counted lgkmcnt.
__device__ __forceinline__ short8 ldsr16(lds_cp p) {
    short8 v;
    asm volatile("ds_read_b128 %0, %1" : "=v"(v) : "v"(p));
    return v;
}

// rule #18: counted lgkm wait + sched_barrier(0) so MFMA can't hoist above it
template <int N>
__device__ __forceinline__ void wait_lgkm() {
    static_assert(N == 0 || N == 5 || N == 6, "unsupported count");
    if constexpr (N == 0) asm volatile("s_waitcnt lgkmcnt(0)" ::: "memory");
    else if constexpr (N == 5) asm volatile("s_waitcnt lgkmcnt(5)" ::: "memory");
    else if constexpr (N == 6) asm volatile("s_waitcnt lgkmcnt(6)" ::: "memory");
    __builtin_amdgcn_sched_barrier(0);
}

__device__ __forceinline__ unsigned short f2bf(float f) {
    union { float f; uint32_t u; } v;
    v.f = f;
    uint32_t u = v.u;
    u += 0x7FFFu + ((u >> 16) & 1u);
    return (unsigned short)(u >> 16);
}

// ---------------- weight prep: transpose fp32 [R][C] -> bf16 [C][R] ----------------
__global__ __launch_bounds__(1024) void transpose_to_bf16(
    const float* __restrict__ src, unsigned short* __restrict__ dst, int R, int C)
{
    __shared__ float tile[32][33];
    const int c0 = blockIdx.x * 32, r0 = blockIdx.y * 32;
    const int tx = threadIdx.x, ty = threadIdx.y;
    tile[ty][tx] = src[(size_t)(r0 + ty) * C + (c0 + tx)];
    __syncthreads();
    dst[(size_t)(c0 + ty) * R + (r0 + tx)] = f2bf(tile[tx][ty]);
}

// ---------------- structural features + pack x = [feat | s] as bf16 ----------------
__global__ __launch_bounds__(64) void struct_pack(
    const float* __restrict__ feat0, const float* __restrict__ feat1,
    const float* __restrict__ pts0,  const float* __restrict__ pts1,
    const int* __restrict__ ids0,    const int* __restrict__ ids1,
    unsigned short* __restrict__ xw)
{
    const int m = blockIdx.x;
    const int t = m / 19200;
    const int r = m % 19200;
    const int n = r / 4800;
    const int l = r % 4800;
    const float* feat = t ? feat1 : feat0;
    const float* pts  = (t ? pts1 : pts0) + (size_t)n * (307200 * 3);
    const int*   ids  = (t ? ids1 : ids0) + n * 128;
    const int a = threadIdx.x;  // 0..63

    const int lr = l / 80, lc = l % 80;
    const int p  = (lr * 8) * 640 + lc * 8;
    const float cx = pts[p * 3 + 0], cy = pts[p * 3 + 1], cz = pts[p * 3 + 2];

    const int id0 = ids[a], id1 = ids[a + 64];
    const float d0x = cx - pts[id0 * 3 + 0];
    const float d0y = cy - pts[id0 * 3 + 1];
    const float d0z = cz - pts[id0 * 3 + 2];
    const float d0d = d0x * d0x + d0y * d0y + d0z * d0z;
    const float d1x = cx - pts[id1 * 3 + 0];
    const float d1y = cy - pts[id1 * 3 + 1];
    const float d1z = cz - pts[id1 * 3 + 2];
    const float d1d = d1x * d1x + d1y * d1y + d1z * d1z;

    float p0 = fabsf(d0x) + fabsf(d1x);
    float p1 = fabsf(d0y) + fabsf(d1y);
    float p2 = fabsf(d0z) + fabsf(d1z);
    float p3 = d0d + d1d;
#pragma unroll
    for (int off = 32; off; off >>= 1) {
        p0 += __shfl_xor(p0, off);
        p1 += __shfl_xor(p1, off);
        p2 += __shfl_xor(p2, off);
        p3 += __shfl_xor(p3, off);
    }
    const float i0 = 1.0f / p0, i1 = 1.0f / p1, i2 = 1.0f / p2, i3 = 1.0f / p3;

    unsigned short* xrow = xw + (size_t)m * 768;
    const float* frow = feat + (size_t)(n * 4800 + l) * 256;
    const float4 fv = ((const float4*)frow)[a];
    short4v s4;
    s4.x = (short)f2bf(fv.x); s4.y = (short)f2bf(fv.y);
    s4.z = (short)f2bf(fv.z); s4.w = (short)f2bf(fv.w);
    *(short4v*)(xrow + a * 4) = s4;

    xrow[256 + 0 * 128 + a]      = f2bf(d0x * i0);
    xrow[256 + 0 * 128 + a + 64] = f2bf(d1x * i0);
    xrow[256 + 1 * 128 + a]      = f2bf(d0y * i1);
    xrow[256 + 1 * 128 + a + 64] = f2bf(d1y * i1);
    xrow[256 + 2 * 128 + a]      = f2bf(d0z * i2);
    xrow[256 + 2 * 128 + a + 64] = f2bf(d1z * i2);
    xrow[256 + 3 * 128 + a]      = f2bf(d0d * i3);
    xrow[256 + 3 * 128 + a + 64] = f2bf(d1d * i3);
}

// ---------------- 8-wave 32x32x16-MFMA GEMM, 4 ks-clusters, counted waits ----------
// C = act(A @ Bt^T + bias). A:[M,K] bf16, Bt:[N,K] bf16 (pre-transposed weight).
// Waves 2M x 4N. Wave tile (AFR*32) x (BFR*32) = 128x64 (G1) / 128x32 (G2).
// BM=256, BN=4*BFR*32, BK=64. LDS: A ring-3 (32KB slots, stage t+2) + B ring-2 (stage t+1).
// MFMA: v_mfma_f32_32x32x16_bf16 (2x FLOP/inst vs 16x16x32; 2495 TF ceiling).
// Per K-tile: 4 ks-clusters (K=16 each); reads for cluster ks+1 issued before waiting
// on cluster ks (counted lgkmcnt, never 0 until last). Boundary: vmcnt(4) + s_barrier
// (A(t+2) stays in flight; A(t+1)+B(t+1) proven landed). Zero-conflict XOR swizzle
// (chunk ^= row&7), inverse pre-applied on staging global source (m173) - rounds 2-7.
template <int AFR, int BFR, bool RELU, bool OUT_BF16>
__global__ __launch_bounds__(512, 2) void gemm_t(
    const unsigned short* __restrict__ A,
    const unsigned short* __restrict__ Bt,
    const float* __restrict__ bias,
    void* __restrict__ Cout,
    int K, int N, int ntx, int q8, int r8)
{
    constexpr int BM = 2 * AFR * 32;          // 256
    constexpr int BN = 4 * BFR * 32;          // 256 or 128
    constexpr int ASLOT = BM * 128;           // 32 KB (BK=64 rows of 128B)
    constexpr int BSLOT = BN * 128;
    constexpr int ALD = BM / 64;              // 4
    constexpr int BLD = BN / 64;              // 4 or 2
    constexpr int PERKS = AFR + BFR;          // reads per ks-cluster (6 or 5)
    static_assert(ALD == 4, "vmcnt immediates assume 4 A-loads/wave/tile");

    extern __shared__ char lds[];
    char* ldsB = lds + 3 * ASLOT;
    const int nt = K >> 6;

    const int bid = blockIdx.x;
    const int xcd = bid & 7, idx = bid >> 3;
    const int w = (xcd < r8 ? xcd * (q8 + 1) : r8 * (q8 + 1) + (xcd - r8) * q8) + idx;
    const int n0 = (w % ntx) * BN;
    const int m0 = (w / ntx) * BM;

    const int tid = threadIdx.x;
    const int lane = tid & 63;
    const int wv = tid >> 6;       // 0..7
    const int wr = wv >> 2;        // 0..1 (M)
    const int wc = wv & 3;         // 0..3 (N)

    // staging (pre-swizzled global source, linear LDS dest); 8 rows x 128B per instr
    const int slr = lane >> 3;
    const int kc  = (lane & 7) ^ slr;
    const unsigned short* gA = A  + (size_t)(m0 + wv * 8 + slr) * K + kc * 8;
    const unsigned short* gB = Bt + (size_t)(n0 + wv * 8 + slr) * K + kc * 8;

    auto stA = [&](int slot, int i, int kt) {
        GLDS16(gA + (size_t)i * 64 * K + kt, lds + slot * ASLOT + (i * 64 + wv * 8) * 128);
    };
    auto stB = [&](int slot, int j, int kt) {
        GLDS16(gB + (size_t)j * 64 * K + kt, ldsB + slot * BSLOT + (j * 64 + wv * 8) * 128);
    };

    // fragment reads (32x32x16): lane holds row=lane&31, k=(lane>>5)*8..+8
    const int R32 = lane & 31;
    const int hi  = lane >> 5;
    int ck[4];
#pragma unroll
    for (int ks = 0; ks < 4; ++ks) ck[ks] = (((ks * 2 + hi) ^ (R32 & 7)) * 16);
    const int aBase = (wr * 128 + R32) * 128;
    const int bBase = (wc * (BFR * 32) + R32) * 128;

    auto LDA = [&](int slot, int mi, int ks) -> short8 {
        return ldsr16((lds_cp)(lds + slot * ASLOT + aBase + mi * 4096 + ck[ks]));
    };
    auto LDB = [&](int slot, int nj, int ks) -> short8 {
        return ldsr16((lds_cp)(ldsB + slot * BSLOT + bBase + nj * 4096 + ck[ks]));
    };

    f32x16 acc[AFR][BFR] = {};
    short8 aF[2][AFR], bF[2][BFR];   // ks-parity double buffer

    // ---- prologue: A(0), B(0), A(1); keep A(1) in flight
    {
#pragma unroll
        for (int i = 0; i < ALD; ++i) stA(0, i, 0);
#pragma unroll
        for (int j = 0; j < BLD; ++j) stB(0, j, 0);
        if (nt > 1) {
#pragma unroll
            for (int i = 0; i < ALD; ++i) stA(1, i, 64);
            asm volatile("s_waitcnt vmcnt(4)" ::: "memory");
        } else {
            asm volatile("s_waitcnt vmcnt(0)" ::: "memory");
        }
        __builtin_amdgcn_s_barrier();
    }

    int cb3 = 0;  // t % 3
    for (int t = 0; t < nt; ++t) {
        const int cb2 = t & 1;
        const int sb2 = cb2 ^ 1;
        int sa3 = cb3 + 2; if (sa3 >= 3) sa3 -= 3;
        const int kt1 = (t + 1) << 6;
        const int kt2 = (t + 2) << 6;
        const bool stb = (t + 1) < nt;
        const bool sta = (t + 2) < nt;

        // R(ks0) -> set0 ; R(ks1) -> set1
#pragma unroll
        for (int mi = 0; mi < AFR; ++mi) aF[0][mi] = LDA(cb3, mi, 0);
#pragma unroll
        for (int nj = 0; nj < BFR; ++nj) bF[0][nj] = LDB(cb2, nj, 0);
#pragma unroll
        for (int mi = 0; mi < AFR; ++mi) aF[1][mi] = LDA(cb3, mi, 1);
#pragma unroll
        for (int nj = 0; nj < BFR; ++nj) bF[1][nj] = LDB(cb2, nj, 1);
        // stage B(t+1) (its buffer was sealed at t-1's boundary)
        if (stb) {
#pragma unroll
            for (int j = 0; j < BLD; ++j) stB(sb2, j, kt1);
        }

        // C(ks0) once set0 landed (set1 still in flight)
        wait_lgkm<PERKS>();
        __builtin_amdgcn_s_setprio(1);
#pragma unroll
        for (int mi = 0; mi < AFR; ++mi)
#pragma unroll
            for (int nj = 0; nj < BFR; ++nj)
                acc[mi][nj] = __builtin_amdgcn_mfma_f32_32x32x16_bf16(aF[0][mi], bF[0][nj], acc[mi][nj], 0, 0, 0);
        __builtin_amdgcn_s_setprio(0);

        // R(ks2) -> set0 ; stage A(t+2)
#pragma unroll
        for (int mi = 0; mi < AFR; ++mi) aF[0][mi] = LDA(cb3, mi, 2);
#pragma unroll
        for (int nj = 0; nj < BFR; ++nj) bF[0][nj] = LDB(cb2, nj, 2);
        if (sta) { stA(sa3, 0, kt2); stA(sa3, 1, kt2); stA(sa3, 2, kt2); stA(sa3, 3, kt2); }

        // C(ks1)
        wait_lgkm<PERKS>();
        __builtin_amdgcn_s_setprio(1);
#pragma unroll
        for (int mi = 0; mi < AFR; ++mi)
#pragma unroll
            for (int nj = 0; nj < BFR; ++nj)
                acc[mi][nj] = __builtin_amdgcn_mfma_f32_32x32x16_bf16(aF[1][mi], bF[1][nj], acc[mi][nj], 0, 0, 0);
        __builtin_amdgcn_s_setprio(0);

        // R(ks3) -> set1
#pragma unroll
        for (int mi = 0; mi < AFR; ++mi) aF[1][mi] = LDA(cb3, mi, 3);
#pragma unroll
        for (int nj = 0; nj < BFR; ++nj) bF[1][nj] = LDB(cb2, nj, 3);

        // C(ks2)
        wait_lgkm<PERKS>();
        __builtin_amdgcn_s_setprio(1);
#pragma unroll
        for (int mi = 0; mi < AFR; ++mi)
#pragma unroll
            for (int nj = 0; nj < BFR; ++nj)
                acc[mi][nj] = __builtin_amdgcn_mfma_f32_32x32x16_bf16(aF[0][mi], bF[0][nj], acc[mi][nj], 0, 0, 0);
        __builtin_amdgcn_s_setprio(0);

        // C(ks3)
        wait_lgkm<0>();
        __builtin_amdgcn_s_setprio(1);
#pragma unroll
        for (int mi = 0; mi < AFR; ++mi)
#pragma unroll
            for (int nj = 0; nj < BFR; ++nj)
                acc[mi][nj] = __builtin_amdgcn_mfma_f32_32x32x16_bf16(aF[1][mi], bF[1][nj], acc[mi][nj], 0, 0, 0);
        __builtin_amdgcn_s_setprio(0);

        // ---- tile boundary: counted vmcnt (A(t+2) stays in flight), collective barrier
        if (t + 1 < nt) {
            if (sta) asm volatile("s_waitcnt vmcnt(4)" ::: "memory");
            else     asm volatile("s_waitcnt vmcnt(0)" ::: "memory");
            __builtin_amdgcn_s_barrier();
        }
        cb3 = (cb3 + 1 == 3) ? 0 : cb3 + 1;
    }

    // epilogue: 32x32 C/D layout (m74/m101): col=lane&31, row=(reg&3)+8*(reg>>2)+4*(lane>>5)
    const int ccol = lane & 31;
#pragma unroll
    for (int nj = 0; nj < BFR; ++nj) {
        const int col = n0 + wc * (BFR * 32) + nj * 32 + ccol;
        const float bv = bias[col];
#pragma unroll
        for (int mi = 0; mi < AFR; ++mi) {
#pragma unroll
            for (int rg = 0; rg < 16; ++rg) {
                const int row = m0 + wr * 128 + mi * 32 + (rg & 3) + 8 * (rg >> 2) + 4 * hi;
                float v = acc[mi][nj][rg] + bv;
                if (RELU) v = fmaxf(v, 0.0f);
                if (OUT_BF16) {
                    ((unsigned short*)Cout)[(size_t)row * N + col] = f2bf(v);
                } else {
                    ((float*)Cout)[(size_t)row * N + col] = v;
                }
            }
        }
    }
}

extern "C" void kernel_launch(void* const* d_in, const int* in_sizes, int n_in,
                              void* d_out, int out_size, void* d_ws, size_t ws_size,
                              hipStream_t stream) {
    const float* feat0 = (const float*)d_in[0];
    const float* feat1 = (const float*)d_in[1];
    const float* pts0  = (const float*)d_in[2];
    const float* pts1  = (const float*)d_in[3];
    const int*   ids0  = (const int*)d_in[4];
    const int*   ids1  = (const int*)d_in[5];
    const float* W1    = (const float*)d_in[6];
    const float* b1    = (const float*)d_in[7];
    const float* W2    = (const float*)d_in[8];
    const float* b2    = (const float*)d_in[9];
    float* out = (float*)d_out;

    char* ws = (char*)d_ws;
    unsigned short* xw  = (unsigned short*)(ws);
    unsigned short* h   = (unsigned short*)(ws + 58982400);
    unsigned short* w1t = (unsigned short*)(ws + 117964800);
    unsigned short* w2t = (unsigned short*)(ws + 119144448);

    // GEMM1: 256x256 tile (AFR=4, BFR=2): LDS = 3*32KB (A) + 2*32KB (B) = 160KB
    const int LDS1 = 3 * 32768 + 2 * 32768;
    // GEMM2: 256x128 tile (AFR=4, BFR=1): LDS = 3*32KB + 2*16KB = 128KB
    const int LDS2 = 3 * 32768 + 2 * 16384;
    (void)hipFuncSetAttribute((const void*)&gemm_t<4, 2, true, true>,
                              hipFuncAttributeMaxDynamicSharedMemorySize, LDS1);
    (void)hipFuncSetAttribute((const void*)&gemm_t<4, 1, false, false>,
                              hipFuncAttributeMaxDynamicSharedMemorySize, LDS2);

    dim3 tb(32, 32);
    transpose_to_bf16<<<dim3(768 / 32, 768 / 32), tb, 0, stream>>>(W1, w1t, 768, 768);
    transpose_to_bf16<<<dim3(256 / 32, 768 / 32), tb, 0, stream>>>(W2, w2t, 768, 256);

    struct_pack<<<38400, 64, 0, stream>>>(feat0, feat1, pts0, pts1, ids0, ids1, xw);

    // GEMM1: h = relu(x @ W1 + b1)  M=38400, N=768 -> tiles 150m x 3n = 450 wg (q=56, r=2)
    gemm_t<4, 2, true, true><<<450, 512, LDS1, stream>>>(xw, w1t, b1, (void*)h, 768, 768, 3, 56, 2);
    // GEMM2: out = h @ W2 + b2      M=38400, N=256 -> tiles 150m x 2n = 300 wg (q=37, r=4)
    gemm_t<4, 1, false, false><<<300, 512, LDS2, stream>>>(h, w2t, b2, (void*)out, 768, 256, 2, 37, 4);
}

// Round 9
// 112.880 us; speedup vs baseline: 1.0683x; 1.0683x over previous
//
#include <hip/hip_runtime.h>
#include <stdint.h>
#include <stddef.h>

typedef __attribute__((ext_vector_type(8))) short short8;
typedef __attribute__((ext_vector_type(4))) short short4v;
typedef __attribute__((ext_vector_type(4))) float f32x4;

typedef const __attribute__((address_space(3))) char* lds_cp;

#define GLDS16(gp, lp)                                                        \
    __builtin_amdgcn_global_load_lds(                                         \
        (const __attribute__((address_space(1))) void*)(gp),                  \
        (__attribute__((address_space(3))) void*)(lp), 16, 0, 0)

// Opaque LDS read: no compiler-inserted waits; completion via counted lgkmcnt.
__device__ __forceinline__ short8 ldsr16(lds_cp p) {
    short8 v;
    asm volatile("ds_read_b128 %0, %1" : "=v"(v) : "v"(p));
    return v;
}

// rule #18: counted lgkm wait + sched_barrier(0) so MFMA can't hoist above it
template <int N>
__device__ __forceinline__ void wait_lgkm() {
    static_assert(N == 0 || N == 2 || N == 4 || N == 8, "unsupported count");
    if constexpr (N == 0) asm volatile("s_waitcnt lgkmcnt(0)" ::: "memory");
    else if constexpr (N == 2) asm volatile("s_waitcnt lgkmcnt(2)" ::: "memory");
    else if constexpr (N == 4) asm volatile("s_waitcnt lgkmcnt(4)" ::: "memory");
    else if constexpr (N == 8) asm volatile("s_waitcnt lgkmcnt(8)" ::: "memory");
    __builtin_amdgcn_sched_barrier(0);
}

template <int N>
__device__ __forceinline__ void wait_vm() {
    static_assert(N == 0 || N == 2 || N == 4, "unsupported count");
    if constexpr (N == 0) asm volatile("s_waitcnt vmcnt(0)" ::: "memory");
    else if constexpr (N == 2) asm volatile("s_waitcnt vmcnt(2)" ::: "memory");
    else if constexpr (N == 4) asm volatile("s_waitcnt vmcnt(4)" ::: "memory");
}

__device__ __forceinline__ unsigned short f2bf(float f) {
    union { float f; uint32_t u; } v;
    v.f = f;
    uint32_t u = v.u;
    u += 0x7FFFu + ((u >> 16) & 1u);
    return (unsigned short)(u >> 16);
}

// ---------------- weight prep: both transposes in ONE launch ----------------
// blocks 0..575: W1 768x768 -> w1t; blocks 576..767: W2 768x256 -> w2t
__global__ __launch_bounds__(1024) void transpose_w(
    const float* __restrict__ W1, const float* __restrict__ W2,
    unsigned short* __restrict__ w1t, unsigned short* __restrict__ w2t)
{
    __shared__ float tile[32][33];
    int b = blockIdx.x;
    const float* src; unsigned short* dst; int R, C, bx, by;
    if (b < 576) { src = W1; dst = w1t; R = 768; C = 768; bx = b % 24; by = b / 24; }
    else { b -= 576; src = W2; dst = w2t; R = 768; C = 256; bx = b % 8; by = b / 8; }
    const int c0 = bx * 32, r0 = by * 32;
    const int tx = threadIdx.x, ty = threadIdx.y;
    tile[ty][tx] = src[(size_t)(r0 + ty) * C + (c0 + tx)];
    __syncthreads();
    dst[(size_t)(c0 + ty) * R + (r0 + tx)] = f2bf(tile[tx][ty]);
}

// ---------------- structural features + pack x = [feat | s] as bf16 ----------------
// 4 waves per block (one (t,n,l) each); lane a handles anchors a and a+64; shfl reduce.
__global__ __launch_bounds__(256) void struct_pack(
    const float* __restrict__ feat0, const float* __restrict__ feat1,
    const float* __restrict__ pts0,  const float* __restrict__ pts1,
    const int* __restrict__ ids0,    const int* __restrict__ ids1,
    unsigned short* __restrict__ xw)
{
    const int m = blockIdx.x * 4 + (threadIdx.x >> 6);
    const int t = m / 19200;
    const int r = m % 19200;
    const int n = r / 4800;
    const int l = r % 4800;
    const float* feat = t ? feat1 : feat0;
    const float* pts  = (t ? pts1 : pts0) + (size_t)n * (307200 * 3);
    const int*   ids  = (t ? ids1 : ids0) + n * 128;
    const int a = threadIdx.x & 63;  // lane

    const int lr = l / 80, lc = l % 80;
    const int p  = (lr * 8) * 640 + lc * 8;
    const float cx = pts[p * 3 + 0], cy = pts[p * 3 + 1], cz = pts[p * 3 + 2];

    const int id0 = ids[a], id1 = ids[a + 64];
    const float d0x = cx - pts[id0 * 3 + 0];
    const float d0y = cy - pts[id0 * 3 + 1];
    const float d0z = cz - pts[id0 * 3 + 2];
    const float d0d = d0x * d0x + d0y * d0y + d0z * d0z;
    const float d1x = cx - pts[id1 * 3 + 0];
    const float d1y = cy - pts[id1 * 3 + 1];
    const float d1z = cz - pts[id1 * 3 + 2];
    const float d1d = d1x * d1x + d1y * d1y + d1z * d1z;

    float p0 = fabsf(d0x) + fabsf(d1x);
    float p1 = fabsf(d0y) + fabsf(d1y);
    float p2 = fabsf(d0z) + fabsf(d1z);
    float p3 = d0d + d1d;
#pragma unroll
    for (int off = 32; off; off >>= 1) {
        p0 += __shfl_xor(p0, off);
        p1 += __shfl_xor(p1, off);
        p2 += __shfl_xor(p2, off);
        p3 += __shfl_xor(p3, off);
    }
    const float i0 = 1.0f / p0, i1 = 1.0f / p1, i2 = 1.0f / p2, i3 = 1.0f / p3;

    unsigned short* xrow = xw + (size_t)m * 768;
    const float* frow = feat + (size_t)(n * 4800 + l) * 256;
    const float4 fv = ((const float4*)frow)[a];
    short4v s4;
    s4.x = (short)f2bf(fv.x); s4.y = (short)f2bf(fv.y);
    s4.z = (short)f2bf(fv.z); s4.w = (short)f2bf(fv.w);
    *(short4v*)(xrow + a * 4) = s4;

    xrow[256 + 0 * 128 + a]      = f2bf(d0x * i0);
    xrow[256 + 0 * 128 + a + 64] = f2bf(d1x * i0);
    xrow[256 + 1 * 128 + a]      = f2bf(d0y * i1);
    xrow[256 + 1 * 128 + a + 64] = f2bf(d1y * i1);
    xrow[256 + 2 * 128 + a]      = f2bf(d0z * i2);
    xrow[256 + 2 * 128 + a + 64] = f2bf(d1z * i2);
    xrow[256 + 3 * 128 + a]      = f2bf(d0d * i3);
    xrow[256 + 3 * 128 + a + 64] = f2bf(d1d * i3);
}

// ---------------- 8-wave barrier-free-intra-tile MFMA GEMM (r6 structure) ----------
// C = act(A @ Bt^T + bias). A:[M,K] bf16, Bt:[N,K] bf16 (pre-transposed weight).
// BM = WRM*MI*16, BN = WRN*NJ*16, BK = 64. LDS: A ring-3 (stage t+2) + B ring-2 (stage t+1).
// No intra-tile barriers: ds_reads issued in groups, consumed via counted lgkmcnt
// (DS completes in order). One boundary per tile: s_waitcnt vmcnt(ALD) + s_barrier
// (A(t+2)'s loads stay in flight; A(t+1)+B(t+1) proven landed).
// Zero-conflict XOR swizzle (chunk ^= row&7), inverse pre-applied on the staging
// GLOBAL source so LDS dest stays linear (m173) - measured 0 conflicts rounds 2-7.
template <int MI, int NJ, int WRN_LOG, bool RELU, bool OUT_BF16>
__global__ __launch_bounds__(512, 2) void gemm_t(
    const unsigned short* __restrict__ A,
    const unsigned short* __restrict__ Bt,
    const float* __restrict__ bias,
    void* __restrict__ Cout,
    int K, int N, int ntx, int q8, int r8)
{
    constexpr int WRN = 1 << WRN_LOG;
    constexpr int WRM = 8 / WRN;
    constexpr int BM = WRM * MI * 16;
    constexpr int BN = WRN * NJ * 16;
    constexpr int ASLOT = BM * 128;
    constexpr int BSLOT = BN * 128;
    constexpr int ALD = BM / 64;
    constexpr int BLD = BN / 64;

    extern __shared__ char lds[];
    char* ldsB = lds + 3 * ASLOT;
    const int nt = K >> 6;

    const int bid = blockIdx.x;
    const int xcd = bid & 7, idx = bid >> 3;
    const int w = (xcd < r8 ? xcd * (q8 + 1) : r8 * (q8 + 1) + (xcd - r8) * q8) + idx;
    const int n0 = (w % ntx) * BN;
    const int m0 = (w / ntx) * BM;

    const int tid = threadIdx.x;
    const int lane = tid & 63;
    const int wv = tid >> 6;
    const int wr = wv >> WRN_LOG;
    const int wc = wv & (WRN - 1);

    // staging (pre-swizzled global source, linear LDS dest)
    const int slr = lane >> 3;
    const int kc  = (lane & 7) ^ slr;
    const unsigned short* gA = A  + (size_t)(m0 + wv * 8 + slr) * K + kc * 8;
    const unsigned short* gB = Bt + (size_t)(n0 + wv * 8 + slr) * K + kc * 8;

    auto stA = [&](int slot, int i, int kt) {
        GLDS16(gA + (size_t)i * 64 * K + kt, lds + slot * ASLOT + (i * 64 + wv * 8) * 128);
    };
    auto stB = [&](int slot, int j, int kt) {
        GLDS16(gB + (size_t)j * 64 * K + kt, ldsB + slot * BSLOT + (j * 64 + wv * 8) * 128);
    };

    // read-side addressing (zero-conflict swizzle)
    const int rsel = lane & 15;
    const int kbh  = lane >> 4;
    const int ck0 = ((kbh) ^ (rsel & 7)) * 16;
    const int ck1 = ((4 + kbh) ^ (rsel & 7)) * 16;
    const int aRowB = (wr * (MI * 16) + rsel) * 128;
    const int bRowB = (wc * (NJ * 16) + rsel) * 128;

    auto LDA = [&](int slot, int mi, int ks) -> short8 {
        return ldsr16((lds_cp)(lds + slot * ASLOT + aRowB + mi * 2048 + (ks ? ck1 : ck0)));
    };
    auto LDB = [&](int slot, int nj, int ks) -> short8 {
        return ldsr16((lds_cp)(ldsB + slot * BSLOT + bRowB + nj * 2048 + (ks ? ck1 : ck0)));
    };

    f32x4 acc[MI][NJ] = {};
    short8 aL[MI / 2], aH[MI / 2], aL1[MI / 2], aH1[MI / 2], bF0[NJ], bF1[NJ];

    // ---- prologue: A(0), B(0), A(1); keep A(1) in flight
    {
#pragma unroll
        for (int i = 0; i < ALD; ++i) stA(0, i, 0);
#pragma unroll
        for (int j = 0; j < BLD; ++j) stB(0, j, 0);
        if (nt > 1) {
#pragma unroll
            for (int i = 0; i < ALD; ++i) stA(1, i, 64);
            wait_vm<ALD>();
        } else {
            wait_vm<0>();
        }
        __builtin_amdgcn_s_barrier();
    }

    int cb3 = 0;  // t % 3
    for (int t = 0; t < nt; ++t) {
        const int cb2 = t & 1;
        const int sb2 = cb2 ^ 1;
        int sa3 = cb3 + 2; if (sa3 >= 3) sa3 -= 3;
        const int kt1 = (t + 1) << 6;
        const int kt2 = (t + 2) << 6;
        const bool stb = (t + 1) < nt;
        const bool sta = (t + 2) < nt;

        // ---- G1: B(ks0) + A-lo(ks0); G2: A-hi(ks0)
#pragma unroll
        for (int nj = 0; nj < NJ; ++nj) bF0[nj] = LDB(cb2, nj, 0);
#pragma unroll
        for (int mi = 0; mi < MI / 2; ++mi) aL[mi] = LDA(cb3, mi, 0);
#pragma unroll
        for (int mi = 0; mi < MI / 2; ++mi) aH[mi] = LDA(cb3, MI / 2 + mi, 0);

        // ---- c1: lo x all (ks0) once G1 landed (G2 may still be in flight)
        wait_lgkm<MI / 2>();
        __builtin_amdgcn_s_setprio(1);
#pragma unroll
        for (int mi = 0; mi < MI / 2; ++mi)
#pragma unroll
            for (int nj = 0; nj < NJ; ++nj)
                acc[mi][nj] = __builtin_amdgcn_mfma_f32_16x16x32_bf16(aL[mi], bF0[nj], acc[mi][nj], 0, 0, 0);
        __builtin_amdgcn_s_setprio(0);

        // ---- G3: B(ks1); stage B(t+1)
#pragma unroll
        for (int nj = 0; nj < NJ; ++nj) bF1[nj] = LDB(cb2, nj, 1);
        if (stb) {
#pragma unroll
            for (int j = 0; j < BLD; ++j) stB(sb2, j, kt1);
        }

        // ---- c2: hi x all (ks0) once G2 landed
        wait_lgkm<NJ>();
        __builtin_amdgcn_s_setprio(1);
#pragma unroll
        for (int mi = 0; mi < MI / 2; ++mi)
#pragma unroll
            for (int nj = 0; nj < NJ; ++nj)
                acc[MI / 2 + mi][nj] = __builtin_amdgcn_mfma_f32_16x16x32_bf16(aH[mi], bF0[nj], acc[MI / 2 + mi][nj], 0, 0, 0);
        __builtin_amdgcn_s_setprio(0);

        // ---- G4: A-lo(ks1) + A-hi(ks1); stage A(t+2)
#pragma unroll
        for (int mi = 0; mi < MI / 2; ++mi) aL1[mi] = LDA(cb3, mi, 1);
#pragma unroll
        for (int mi = 0; mi < MI / 2; ++mi) aH1[mi] = LDA(cb3, MI / 2 + mi, 1);
        if (sta) {
#pragma unroll
            for (int i = 0; i < ALD; ++i) stA(sa3, i, kt2);
        }

        // ---- c3: lo x all (ks1) once B(ks1)+A-lo(ks1) landed
        wait_lgkm<MI / 2>();
        __builtin_amdgcn_s_setprio(1);
#pragma unroll
        for (int mi = 0; mi < MI / 2; ++mi)
#pragma unroll
            for (int nj = 0; nj < NJ; ++nj)
                acc[mi][nj] = __builtin_amdgcn_mfma_f32_16x16x32_bf16(aL1[mi], bF1[nj], acc[mi][nj], 0, 0, 0);
        __builtin_amdgcn_s_setprio(0);

        // ---- c4: hi x all (ks1) once everything landed
        wait_lgkm<0>();
        __builtin_amdgcn_s_setprio(1);
#pragma unroll
        for (int mi = 0; mi < MI / 2; ++mi)
#pragma unroll
            for (int nj = 0; nj < NJ; ++nj)
                acc[MI / 2 + mi][nj] = __builtin_amdgcn_mfma_f32_16x16x32_bf16(aH1[mi], bF1[nj], acc[MI / 2 + mi][nj], 0, 0, 0);
        __builtin_amdgcn_s_setprio(0);

        // ---- tile boundary: counted vmcnt (A(t+2) stays in flight), collective barrier
        if (t + 1 < nt) {
            if (sta) wait_vm<ALD>();
            else     wait_vm<0>();
            __builtin_amdgcn_s_barrier();
        }
        cb3 = (cb3 + 1 == 3) ? 0 : cb3 + 1;
    }

    // epilogue: C/D layout (m89): col = lane&15, row = (lane>>4)*4 + reg
    const int crow = (lane >> 4) * 4;
    const int ccol = lane & 15;
#pragma unroll
    for (int nj = 0; nj < NJ; ++nj) {
        const int col = n0 + wc * (NJ * 16) + nj * 16 + ccol;
        const float bv = bias[col];
#pragma unroll
        for (int mi = 0; mi < MI; ++mi) {
#pragma unroll
            for (int rg = 0; rg < 4; ++rg) {
                const int row = m0 + wr * (MI * 16) + mi * 16 + crow + rg;
                float v = acc[mi][nj][rg] + bv;
                if (RELU) v = fmaxf(v, 0.0f);
                if (OUT_BF16) {
                    ((unsigned short*)Cout)[(size_t)row * N + col] = f2bf(v);
                } else {
                    ((float*)Cout)[(size_t)row * N + col] = v;
                }
            }
        }
    }
}

extern "C" void kernel_launch(void* const* d_in, const int* in_sizes, int n_in,
                              void* d_out, int out_size, void* d_ws, size_t ws_size,
                              hipStream_t stream) {
    const float* feat0 = (const float*)d_in[0];
    const float* feat1 = (const float*)d_in[1];
    const float* pts0  = (const float*)d_in[2];
    const float* pts1  = (const float*)d_in[3];
    const int*   ids0  = (const int*)d_in[4];
    const int*   ids1  = (const int*)d_in[5];
    const float* W1    = (const float*)d_in[6];
    const float* b1    = (const float*)d_in[7];
    const float* W2    = (const float*)d_in[8];
    const float* b2    = (const float*)d_in[9];
    float* out = (float*)d_out;

    char* ws = (char*)d_ws;
    unsigned short* xw  = (unsigned short*)(ws);
    unsigned short* h   = (unsigned short*)(ws + 58982400);
    unsigned short* w1t = (unsigned short*)(ws + 117964800);
    unsigned short* w2t = (unsigned short*)(ws + 119144448);

    // GEMM1: <8,4,2> 256x256 tile, wave tile 128x64; LDS = 3*32K + 2*32K = 160 KB, 1 blk/CU
    const int LDS1 = 3 * 32768 + 2 * 32768;
    // GEMM2: <4,2,2> 128x128 tile, wave tile 64x32; LDS = 3*16K + 2*16K = 80 KB, 2 blk/CU
    const int LDS2 = 3 * 16384 + 2 * 16384;
    (void)hipFuncSetAttribute((const void*)&gemm_t<8, 4, 2, true, true>,
                              hipFuncAttributeMaxDynamicSharedMemorySize, LDS1);
    (void)hipFuncSetAttribute((const void*)&gemm_t<4, 2, 2, false, false>,
                              hipFuncAttributeMaxDynamicSharedMemorySize, LDS2);

    transpose_w<<<768, dim3(32, 32), 0, stream>>>(W1, W2, w1t, w2t);

    struct_pack<<<9600, 256, 0, stream>>>(feat0, feat1, pts0, pts1, ids0, ids1, xw);

    // GEMM1: h = relu(x @ W1 + b1)  M=38400, N=768 -> tiles 150m x 3n = 450 wg (q=56, r=2)
    gemm_t<8, 4, 2, true, true><<<450, 512, LDS1, stream>>>(xw, w1t, b1, (void*)h, 768, 768, 3, 56, 2);
    // GEMM2: out = h @ W2 + b2      M=38400, N=256 -> tiles 300m x 2n = 600 wg (q=75, r=0)
    gemm_t<4, 2, 2, false, false><<<600, 512, LDS2, stream>>>(h, w2t, b2, (void*)out, 768, 256, 2, 75, 0);
}